// Round 1
// baseline (261.064 us; speedup 1.0000x reference)
//
#include <hip/hip_runtime.h>
#include <stdint.h>

#define S_LEN 2048
#define NH 16
#define HD 64
#define CDIM 1024
#define QKV_LD 3072
#define WIN 256

typedef __attribute__((ext_vector_type(8))) short bf16x8;
typedef __attribute__((ext_vector_type(4))) short bf16x4;
typedef __attribute__((ext_vector_type(4))) float f32x4;

__device__ __forceinline__ short f2bf(float f) {
  uint32_t u = __builtin_bit_cast(uint32_t, f);
  u += 0x7fffu + ((u >> 16) & 1u);   // RNE
  return (short)(u >> 16);
}

// ---------------- fp32 -> bf16 conversion ----------------
__global__ void cvt_f32_bf16(const float* __restrict__ in, short* __restrict__ out, int n4) {
  int i = blockIdx.x * 256 + threadIdx.x;
  if (i >= n4) return;
  float4 v = ((const float4*)in)[i];
  bf16x4 o;
  o[0] = f2bf(v.x); o[1] = f2bf(v.y); o[2] = f2bf(v.z); o[3] = f2bf(v.w);
  ((bf16x4*)out)[i] = o;
}

// ---------------- async global->LDS helper ----------------
__device__ __forceinline__ void gl_lds16(const short* g, short* lds) {
  __builtin_amdgcn_global_load_lds(
      (const __attribute__((address_space(1))) uint32_t*)(uintptr_t)g,
      (__attribute__((address_space(3))) uint32_t*)(uintptr_t)lds,
      16, 0, 0);
}

// ---------------- bf16 GEMM: C[m][n] = A[m][k] * Bt[n][k] + bias[n] ----------------
// 128x128 tile, BK=32, 256 threads = 4 waves (2x2), each wave 64x64 via 4x4 16x16x32 MFMA.
template <int BF16OUT>
__global__ __launch_bounds__(256) void gemm_bias(
    const short* __restrict__ A, const short* __restrict__ Bt,
    const float* __restrict__ bias, void* __restrict__ Cout,
    int M, int N, int K)
{
  __shared__ __align__(16) short Asm[128 * 32];
  __shared__ __align__(16) short Bsm[128 * 32];
  const int tid = threadIdx.x;
  const int wave = tid >> 6;
  const int lane = tid & 63;
  const int wm = wave >> 1, wn = wave & 1;
  const int m0 = blockIdx.y * 128, n0 = blockIdx.x * 128;

  // staging: chunk = 16 rows x 32 cols = 1KB, lane l -> row l/4, col (l%4)*8
  const int srow = lane >> 2;
  const int scol = (lane & 3) * 8;
  const short* Ag0 = A + (size_t)(m0 + wave * 16 + srow) * K + scol;
  const short* Ag1 = A + (size_t)(m0 + (wave + 4) * 16 + srow) * K + scol;
  const short* Bg0 = Bt + (size_t)(n0 + wave * 16 + srow) * K + scol;
  const short* Bg1 = Bt + (size_t)(n0 + (wave + 4) * 16 + srow) * K + scol;
  short* lA0 = &Asm[wave * 512];
  short* lA1 = &Asm[(wave + 4) * 512];
  short* lB0 = &Bsm[wave * 512];
  short* lB1 = &Bsm[(wave + 4) * 512];

  f32x4 acc[4][4] = {};

  const int frow = lane & 15;        // M/N-local index within 16x16 frag
  const int fcol = (lane >> 4) * 8;  // K offset

  for (int k0 = 0; k0 < K; k0 += 32) {
    gl_lds16(Ag0 + k0, lA0);
    gl_lds16(Ag1 + k0, lA1);
    gl_lds16(Bg0 + k0, lB0);
    gl_lds16(Bg1 + k0, lB1);
    __syncthreads();   // drains vmcnt -> LDS tiles ready
    bf16x8 af[4], bfv[4];
#pragma unroll
    for (int i = 0; i < 4; i++) {
      af[i]  = *(const bf16x8*)&Asm[(wm * 64 + i * 16 + frow) * 32 + fcol];
      bfv[i] = *(const bf16x8*)&Bsm[(wn * 64 + i * 16 + frow) * 32 + fcol];
    }
#pragma unroll
    for (int mi = 0; mi < 4; mi++)
#pragma unroll
      for (int ni = 0; ni < 4; ni++)
        acc[mi][ni] = __builtin_amdgcn_mfma_f32_16x16x32_bf16(af[mi], bfv[ni], acc[mi][ni], 0, 0, 0);
    __syncthreads();   // protect LDS before next stage
  }

  // epilogue: C/D layout col=lane&15, row=(lane>>4)*4+j  [verified m89/m91]
  const int erow = (lane >> 4) * 4;
  const int ecol = lane & 15;
#pragma unroll
  for (int ni = 0; ni < 4; ni++) {
    int n = n0 + wn * 64 + ni * 16 + ecol;
    float bs = bias[n];
#pragma unroll
    for (int mi = 0; mi < 4; mi++) {
      int m = m0 + wm * 64 + mi * 16 + erow;
#pragma unroll
      for (int j = 0; j < 4; j++) {
        float v = acc[mi][ni][j] + bs;
        if (BF16OUT)
          ((short*)Cout)[(size_t)(m + j) * N + n] = f2bf(v);
        else
          ((float*)Cout)[(size_t)(m + j) * N + n] = v;
      }
    }
  }
}

// ---------------- windowed causal flash attention ----------------
// 256 threads = 4 waves; each wave owns one 16-query tile of one (b,h).
// Swapped QK^T: S^T[key][query] = mfma(K_frag, Q_frag) so all stats/accums in a
// lane share query = lane&15. P^T (S^T D-layout) feeds PV MFMA B-frag directly.
__global__ __launch_bounds__(256) void attn_win(
    const short* __restrict__ qkv, short* __restrict__ ctx)
{
  const int tid = threadIdx.x;
  const int wave = tid >> 6, lane = tid & 63;
  const int grp = blockIdx.x % 32;           // 32 groups * 4 waves = 128 q-tiles
  const int h = (blockIdx.x / 32) % NH;
  const int b = blockIdx.x / (32 * NH);
  const int qb = (grp * 4 + wave) * 16;

  const int cl = lane & 15;   // query-local
  const int g  = lane >> 4;   // lane group

  const size_t rowQ = (size_t)(b * S_LEN + qb + cl) * QKV_LD + h * HD;
  bf16x8 qf0 = *(const bf16x8*)&qkv[rowQ + g * 8];
  bf16x8 qf1 = *(const bf16x8*)&qkv[rowQ + 32 + g * 8];

  float m_run = -1e30f, l_run = 0.f;
  f32x4 acc[4] = {};          // ctx^T chunks: d = c*16 + 4g + j, query = cl
  const f32x4 zero = {};

  const int kstart = qb >= WIN ? qb - WIN : 0;
  const int q_glob = qb + cl;

  for (int k0 = kstart; k0 <= qb; k0 += 16) {
    const size_t rowK = (size_t)(b * S_LEN + k0 + cl) * QKV_LD + CDIM + h * HD;
    bf16x8 kf0 = *(const bf16x8*)&qkv[rowK + g * 8];
    bf16x8 kf1 = *(const bf16x8*)&qkv[rowK + 32 + g * 8];
    f32x4 st = __builtin_amdgcn_mfma_f32_16x16x32_bf16(kf0, qf0, zero, 0, 0, 0);
    st = __builtin_amdgcn_mfma_f32_16x16x32_bf16(kf1, qf1, st, 0, 0, 0);
    // st[e] = S^T[key = k0+4g+e][query = qb+cl] (unscaled)

    float s[4]; bool ok[4];
    float mt = -1e30f;
#pragma unroll
    for (int e = 0; e < 4; e++) {
      int key = k0 + 4 * g + e;
      ok[e] = (key <= q_glob) && (q_glob - key < WIN);
      s[e] = st[e] * 0.125f;
      if (ok[e]) mt = fmaxf(mt, s[e]);
    }
    mt = fmaxf(mt, __shfl_xor(mt, 16, 64));
    mt = fmaxf(mt, __shfl_xor(mt, 32, 64));
    float m_new = fmaxf(m_run, mt);
    float scale = __expf(m_run - m_new);   // both -1e30 -> 1, harmless (acc,l are 0)
    float p[4]; float ls = 0.f;
#pragma unroll
    for (int e = 0; e < 4; e++) {
      p[e] = ok[e] ? __expf(s[e] - m_new) : 0.f;
      ls += p[e];
    }
    ls += __shfl_xor(ls, 16, 64);
    ls += __shfl_xor(ls, 32, 64);
    l_run = l_run * scale + ls;
    m_run = m_new;
#pragma unroll
    for (int c = 0; c < 4; c++) acc[c] *= scale;

    bf16x4 pf;   // B-frag: B[k=4g+e][col=cl] == S^T D-layout, direct reuse
#pragma unroll
    for (int e = 0; e < 4; e++) pf[e] = f2bf(p[e]);

    const size_t rowV = (size_t)(b * S_LEN + k0 + 4 * g) * QKV_LD + 2 * CDIM + h * HD + cl;
#pragma unroll
    for (int c = 0; c < 4; c++) {
      bf16x4 vf;   // A-frag: A[row=cl][k=4g+e] = V[k0+4g+e][c*16+cl]
#pragma unroll
      for (int e = 0; e < 4; e++)
        vf[e] = qkv[rowV + (size_t)e * QKV_LD + c * 16];
      acc[c] = __builtin_amdgcn_mfma_f32_16x16x16bf16_1k(vf, pf, acc[c], 0, 0, 0);
    }
  }

  const float inv_l = 1.f / l_run;
  const size_t rowO = (size_t)(b * S_LEN + qb + cl) * CDIM + h * HD;
#pragma unroll
  for (int c = 0; c < 4; c++)
#pragma unroll
    for (int j = 0; j < 4; j++)
      ctx[rowO + c * 16 + 4 * g + j] = f2bf(acc[c][j] * inv_l);
}

// ---------------- launcher ----------------
extern "C" void kernel_launch(void* const* d_in, const int* in_sizes, int n_in,
                              void* d_out, int out_size, void* d_ws, size_t ws_size,
                              hipStream_t stream) {
  const float* x      = (const float*)d_in[0];
  const float* W_qkv  = (const float*)d_in[1];
  const float* b_qkv  = (const float*)d_in[2];
  const float* W_proj = (const float*)d_in[3];
  const float* b_proj = (const float*)d_in[4];
  float* out = (float*)d_out;

  const int BS = 4 * S_LEN;  // 8192 rows
  char* ws = (char*)d_ws;
  short* qkv_bf = (short*)ws;                              // [8192][3072] bf16 (48MB)
  short* x_bf   = (short*)(ws + (size_t)BS * QKV_LD * 2);  // [8192][1024] (16MB)
  short* wq_bf  = x_bf + (size_t)BS * CDIM;                // [3072][1024] (6MB)
  short* wp_bf  = wq_bf + (size_t)QKV_LD * CDIM;           // [1024][1024] (2MB)
  short* ctx_bf = wp_bf + (size_t)CDIM * CDIM;             // [8192][1024] (16MB)

  int n4 = BS * CDIM / 4;
  cvt_f32_bf16<<<(n4 + 255) / 256, 256, 0, stream>>>(x, x_bf, n4);
  n4 = QKV_LD * CDIM / 4;
  cvt_f32_bf16<<<(n4 + 255) / 256, 256, 0, stream>>>(W_qkv, wq_bf, n4);
  n4 = CDIM * CDIM / 4;
  cvt_f32_bf16<<<(n4 + 255) / 256, 256, 0, stream>>>(W_proj, wp_bf, n4);

  dim3 g1(QKV_LD / 128, BS / 128);
  gemm_bias<1><<<g1, 256, 0, stream>>>(x_bf, wq_bf, b_qkv, qkv_bf, BS, QKV_LD, CDIM);

  attn_win<<<4 * NH * 32, 256, 0, stream>>>(qkv_bf, ctx_bf);

  dim3 g2(CDIM / 128, BS / 128);
  gemm_bias<0><<<g2, 256, 0, stream>>>(ctx_bf, wp_bf, b_proj, out, BS, CDIM, CDIM);
}

// Round 2
// 259.669 us; speedup vs baseline: 1.0054x; 1.0054x over previous
//
#include <hip/hip_runtime.h>
#include <stdint.h>

#define S_LEN 2048
#define NH 16
#define HD 64
#define CDIM 1024
#define QKV_LD 3072
#define WIN 256

typedef __attribute__((ext_vector_type(8))) short bf16x8;
typedef __attribute__((ext_vector_type(4))) short bf16x4;
typedef __attribute__((ext_vector_type(4))) float f32x4;

__device__ __forceinline__ short f2bf(float f) {
  uint32_t u = __builtin_bit_cast(uint32_t, f);
  u += 0x7fffu + ((u >> 16) & 1u);   // RNE
  return (short)(u >> 16);
}

// ---------------- fp32 -> bf16 conversion ----------------
__global__ void cvt_f32_bf16(const float* __restrict__ in, short* __restrict__ out, int n4) {
  int i = blockIdx.x * 256 + threadIdx.x;
  if (i >= n4) return;
  float4 v = ((const float4*)in)[i];
  bf16x4 o;
  o[0] = f2bf(v.x); o[1] = f2bf(v.y); o[2] = f2bf(v.z); o[3] = f2bf(v.w);
  ((bf16x4*)out)[i] = o;
}

// ---------------- async global->LDS helper ----------------
__device__ __forceinline__ void gl_lds16(const short* g, short* lds) {
  __builtin_amdgcn_global_load_lds(
      (const __attribute__((address_space(1))) uint32_t*)(uintptr_t)g,
      (__attribute__((address_space(3))) uint32_t*)(uintptr_t)lds,
      16, 0, 0);
}

#define WAITVM(N) asm volatile("s_waitcnt vmcnt(" #N ")" ::: "memory")

// ---------------- 8-phase bf16 GEMM: C[m][n] = A[m][k]*Bt[n][k] + bias[n] ----
// BM=256 BN=128 BK=64, 512 threads = 8 waves (4M x 2N), per-wave 64x64 out.
// LDS 96KB: double-buffered, K-half-split arrays so each stage is contiguous.
// Phase = (mh,kh) quadrant: 8 MFMA between raw barriers; staging schedule:
//   P1: A-kh1(t+1)  P2: B-kh1(t+1)   (other buffer — t+1's kh0 staged last tile)
//   P3: A-kh0(t+2)  P4: B-kh0(t+2)   (this buffer's kh0 regions freed after P2)
// Boundary wait: vmcnt(3) = P3+P4's 3 loads still in flight (never 0 mid-loop).
template <int BF16OUT>
__global__ __launch_bounds__(512) void gemm8p(
    const short* __restrict__ A, const short* __restrict__ Bt,
    const float* __restrict__ bias, void* __restrict__ Cout,
    int M, int N, int K)
{
  __shared__ __align__(16) short Asm[2][2][256 * 32];
  __shared__ __align__(16) short Bsm[2][2][128 * 32];
  const int tid = threadIdx.x;
  const int wave = tid >> 6, lane = tid & 63;
  const int wm = wave >> 1, wn = wave & 1;     // 4 x 2 wave grid
  const int m0 = blockIdx.y * 256, n0 = blockIdx.x * 128;
  const int cl = lane & 15, g = lane >> 4;
  const int NT = K >> 6;                       // 64-wide K-tiles (=16 here)

  const short* Ab = A + (size_t)m0 * K;
  const short* Bb = Bt + (size_t)n0 * K;

  // thread-constant staging geometry (swizzle: 16B chunk ^= (row>>2)&3, applied
  // to the GLOBAL source column; LDS dest stays linear per gload_lds rules)
  const int off0 = tid * 8;                    // element offset, rows 0..127
  const int r0 = off0 >> 5;
  const int cs0 = ((off0 >> 3) & 3) ^ ((r0 >> 2) & 3);
  const int off1 = 4096 + tid * 8;             // rows 128..255 (A only)
  const int r1 = off1 >> 5;
  const int cs1 = ((off1 >> 3) & 3) ^ ((r1 >> 2) & 3);
  const short* AgL0 = Ab + (size_t)r0 * K + cs0 * 8;
  const short* AgL1 = Ab + (size_t)r1 * K + cs1 * 8;
  const short* Bg   = Bb + (size_t)r0 * K + cs0 * 8;

  auto stageA = [&](int t1, int kh) {
    gl_lds16(AgL0 + t1 * 64 + kh * 32, &Asm[t1 & 1][kh][off0]);
    gl_lds16(AgL1 + t1 * 64 + kh * 32, &Asm[t1 & 1][kh][off1]);
  };
  auto stageB = [&](int t1, int kh) {
    gl_lds16(Bg + t1 * 64 + kh * 32, &Bsm[t1 & 1][kh][off0]);
  };

  f32x4 acc[4][4] = {};

  // prologue: tile0 complete + tile1 kh0; allow tile1's 3 loads outstanding
  stageA(0, 0); stageB(0, 0); stageA(0, 1); stageB(0, 1);
  stageA(1, 0); stageB(1, 0);
  WAITVM(3);
  __builtin_amdgcn_s_barrier();

#define DS_A(MH, KH)                                                          \
  _Pragma("unroll") for (int i = 0; i < 2; i++) {                             \
    const int ra = wm * 64 + (MH) * 32 + i * 16 + cl;                         \
    af[i] = *(const bf16x8*)&Asm[bi][KH][ra * 32 + (((g ^ (ra >> 2)) & 3) * 8)]; \
  }
#define DS_B(KH)                                                              \
  _Pragma("unroll") for (int j = 0; j < 4; j++) {                             \
    const int rb = wn * 64 + j * 16 + cl;                                     \
    bfr[j] = *(const bf16x8*)&Bsm[bi][KH][rb * 32 + (((g ^ (rb >> 2)) & 3) * 8)]; \
  }
#define MFMA8(MH)                                                             \
  __builtin_amdgcn_s_barrier();                                               \
  __builtin_amdgcn_s_setprio(1);                                              \
  _Pragma("unroll") for (int i = 0; i < 2; i++)                               \
    _Pragma("unroll") for (int j = 0; j < 4; j++)                             \
      acc[(MH) * 2 + i][j] = __builtin_amdgcn_mfma_f32_16x16x32_bf16(         \
          af[i], bfr[j], acc[(MH) * 2 + i][j], 0, 0, 0);                      \
  __builtin_amdgcn_s_setprio(0);                                              \
  __builtin_amdgcn_s_barrier();

  for (int t = 0; t < NT; ++t) {
    const int bi = t & 1;
    bf16x8 af[2], bfr[4];

    DS_A(0, 0); DS_B(0);
    if (t + 1 < NT) stageA(t + 1, 1);
    MFMA8(0);

    DS_A(1, 0);
    if (t + 1 < NT) stageB(t + 1, 1);
    MFMA8(1);

    DS_A(0, 1); DS_B(1);
    if (t + 2 < NT) stageA(t + 2, 0);
    MFMA8(0);

    DS_A(1, 1);
    if (t + 2 < NT) stageB(t + 2, 0);
    if (t + 2 < NT) { WAITVM(3); } else { WAITVM(0); }
    MFMA8(1);
  }
#undef DS_A
#undef DS_B
#undef MFMA8

  // epilogue: D-layout col=lane&15, row=(lane>>4)*4+e  [m89/m91]
#pragma unroll
  for (int j = 0; j < 4; j++) {
    const int n = n0 + wn * 64 + j * 16 + cl;
    const float bs = bias[n];
#pragma unroll
    for (int a = 0; a < 4; a++) {
      const int mrow = m0 + wm * 64 + (a >> 1) * 32 + (a & 1) * 16 + g * 4;
#pragma unroll
      for (int e = 0; e < 4; e++) {
        const float v = acc[a][j][e] + bs;
        if (BF16OUT) ((short*)Cout)[(size_t)(mrow + e) * N + n] = f2bf(v);
        else         ((float*)Cout)[(size_t)(mrow + e) * N + n] = v;
      }
    }
  }
}

// ---------------- windowed causal flash attention (unchanged, verified) -----
__global__ __launch_bounds__(256) void attn_win(
    const short* __restrict__ qkv, short* __restrict__ ctx)
{
  const int tid = threadIdx.x;
  const int wave = tid >> 6, lane = tid & 63;
  const int grp = blockIdx.x % 32;
  const int h = (blockIdx.x / 32) % NH;
  const int b = blockIdx.x / (32 * NH);
  const int qb = (grp * 4 + wave) * 16;

  const int cl = lane & 15;
  const int g  = lane >> 4;

  const size_t rowQ = (size_t)(b * S_LEN + qb + cl) * QKV_LD + h * HD;
  bf16x8 qf0 = *(const bf16x8*)&qkv[rowQ + g * 8];
  bf16x8 qf1 = *(const bf16x8*)&qkv[rowQ + 32 + g * 8];

  float m_run = -1e30f, l_run = 0.f;
  f32x4 acc[4] = {};
  const f32x4 zero = {};

  const int kstart = qb >= WIN ? qb - WIN : 0;
  const int q_glob = qb + cl;

  for (int k0 = kstart; k0 <= qb; k0 += 16) {
    const size_t rowK = (size_t)(b * S_LEN + k0 + cl) * QKV_LD + CDIM + h * HD;
    bf16x8 kf0 = *(const bf16x8*)&qkv[rowK + g * 8];
    bf16x8 kf1 = *(const bf16x8*)&qkv[rowK + 32 + g * 8];
    f32x4 st = __builtin_amdgcn_mfma_f32_16x16x32_bf16(kf0, qf0, zero, 0, 0, 0);
    st = __builtin_amdgcn_mfma_f32_16x16x32_bf16(kf1, qf1, st, 0, 0, 0);

    float s[4]; bool ok[4];
    float mt = -1e30f;
#pragma unroll
    for (int e = 0; e < 4; e++) {
      int key = k0 + 4 * g + e;
      ok[e] = (key <= q_glob) && (q_glob - key < WIN);
      s[e] = st[e] * 0.125f;
      if (ok[e]) mt = fmaxf(mt, s[e]);
    }
    mt = fmaxf(mt, __shfl_xor(mt, 16, 64));
    mt = fmaxf(mt, __shfl_xor(mt, 32, 64));
    float m_new = fmaxf(m_run, mt);
    float scale = __expf(m_run - m_new);
    float p[4]; float ls = 0.f;
#pragma unroll
    for (int e = 0; e < 4; e++) {
      p[e] = ok[e] ? __expf(s[e] - m_new) : 0.f;
      ls += p[e];
    }
    ls += __shfl_xor(ls, 16, 64);
    ls += __shfl_xor(ls, 32, 64);
    l_run = l_run * scale + ls;
    m_run = m_new;
#pragma unroll
    for (int c = 0; c < 4; c++) acc[c] *= scale;

    bf16x4 pf;
#pragma unroll
    for (int e = 0; e < 4; e++) pf[e] = f2bf(p[e]);

    const size_t rowV = (size_t)(b * S_LEN + k0 + 4 * g) * QKV_LD + 2 * CDIM + h * HD + cl;
#pragma unroll
    for (int c = 0; c < 4; c++) {
      bf16x4 vf;
#pragma unroll
      for (int e = 0; e < 4; e++)
        vf[e] = qkv[rowV + (size_t)e * QKV_LD + c * 16];
      acc[c] = __builtin_amdgcn_mfma_f32_16x16x16bf16_1k(vf, pf, acc[c], 0, 0, 0);
    }
  }

  const float inv_l = 1.f / l_run;
  const size_t rowO = (size_t)(b * S_LEN + qb + cl) * CDIM + h * HD;
#pragma unroll
  for (int c = 0; c < 4; c++)
#pragma unroll
    for (int j = 0; j < 4; j++)
      ctx[rowO + c * 16 + 4 * g + j] = f2bf(acc[c][j] * inv_l);
}

// ---------------- launcher ----------------
extern "C" void kernel_launch(void* const* d_in, const int* in_sizes, int n_in,
                              void* d_out, int out_size, void* d_ws, size_t ws_size,
                              hipStream_t stream) {
  const float* x      = (const float*)d_in[0];
  const float* W_qkv  = (const float*)d_in[1];
  const float* b_qkv  = (const float*)d_in[2];
  const float* W_proj = (const float*)d_in[3];
  const float* b_proj = (const float*)d_in[4];
  float* out = (float*)d_out;

  const int BS = 4 * S_LEN;  // 8192 rows
  char* ws = (char*)d_ws;
  short* qkv_bf = (short*)ws;                              // [8192][3072] bf16
  short* x_bf   = (short*)(ws + (size_t)BS * QKV_LD * 2);  // [8192][1024]
  short* wq_bf  = x_bf + (size_t)BS * CDIM;                // [3072][1024]
  short* wp_bf  = wq_bf + (size_t)QKV_LD * CDIM;           // [1024][1024]
  short* ctx_bf = wp_bf + (size_t)CDIM * CDIM;             // [8192][1024]

  int n4 = BS * CDIM / 4;
  cvt_f32_bf16<<<(n4 + 255) / 256, 256, 0, stream>>>(x, x_bf, n4);
  n4 = QKV_LD * CDIM / 4;
  cvt_f32_bf16<<<(n4 + 255) / 256, 256, 0, stream>>>(W_qkv, wq_bf, n4);
  n4 = CDIM * CDIM / 4;
  cvt_f32_bf16<<<(n4 + 255) / 256, 256, 0, stream>>>(W_proj, wp_bf, n4);

  dim3 g1(QKV_LD / 128, BS / 256);   // 24 x 32 = 768 blocks
  gemm8p<1><<<g1, 512, 0, stream>>>(x_bf, wq_bf, b_qkv, qkv_bf, BS, QKV_LD, CDIM);

  attn_win<<<4 * NH * 32, 256, 0, stream>>>(qkv_bf, ctx_bf);

  dim3 g2(CDIM / 128, BS / 256);     // 8 x 32 = 256 blocks
  gemm8p<0><<<g2, 512, 0, stream>>>(ctx_bf, wp_bf, b_proj, out, BS, CDIM, CDIM);
}

// Round 3
// 249.850 us; speedup vs baseline: 1.0449x; 1.0393x over previous
//
#include <hip/hip_runtime.h>
#include <stdint.h>

#define S_LEN 2048
#define NH 16
#define HD 64
#define CDIM 1024
#define QKV_LD 3072
#define WIN 256

typedef __attribute__((ext_vector_type(8))) short bf16x8;
typedef __attribute__((ext_vector_type(4))) short bf16x4;
typedef __attribute__((ext_vector_type(4))) float f32x4;

__device__ __forceinline__ short f2bf(float f) {
  uint32_t u = __builtin_bit_cast(uint32_t, f);
  u += 0x7fffu + ((u >> 16) & 1u);   // RNE
  return (short)(u >> 16);
}

// ---------------- fp32 -> bf16 conversion ----------------
__global__ void cvt_f32_bf16(const float* __restrict__ in, short* __restrict__ out, int n4) {
  int i = blockIdx.x * 256 + threadIdx.x;
  if (i >= n4) return;
  float4 v = ((const float4*)in)[i];
  bf16x4 o;
  o[0] = f2bf(v.x); o[1] = f2bf(v.y); o[2] = f2bf(v.z); o[3] = f2bf(v.w);
  ((bf16x4*)out)[i] = o;
}

// ---------------- async global->LDS helper ----------------
__device__ __forceinline__ void gl_lds16(const short* g, short* lds) {
  __builtin_amdgcn_global_load_lds(
      (const __attribute__((address_space(1))) uint32_t*)(uintptr_t)g,
      (__attribute__((address_space(3))) uint32_t*)(uintptr_t)lds,
      16, 0, 0);
}

#define WAITVM(N) asm volatile("s_waitcnt vmcnt(" #N ")" ::: "memory")

// ---------- ring-4 pipelined bf16 GEMM: C[m][n] = A[m][k]*Bt[n][k] + bias[n] -
// BM=128 BN=256, K=1024 fixed (32 sub-tiles of K=32). 512 thr = 8 waves (2Mx4N),
// wave-tile 64x64 (acc 4x4). Ring of 4 LDS sub-tile slots (96KB total).
// Phase j: {ds_read frags(j+1) into regs} {stage sub j+3} {vmcnt(3)} {barrier}
//          {16 MFMA on frags(j) read last phase}.
// Read latency hides under barrier; counted vmcnt keeps 1 sub in flight.
// LDS bank swizzle: 16B chunk ^= (row>>1)&3 (read side) with inverse-permuted
// GLOBAL source on the stage side (LDS dest stays linear for global_load_lds).
template <int BF16OUT>
__global__ __launch_bounds__(512) void gemm_ring(
    const short* __restrict__ A, const short* __restrict__ Bt,
    const float* __restrict__ bias, void* __restrict__ Cout, int N)
{
  constexpr int K = 1024;
  constexpr int NSUB = 32;
  __shared__ __align__(16) short Asm[4][128 * 32];
  __shared__ __align__(16) short Bsm[4][256 * 32];
  const int tid = threadIdx.x, wave = tid >> 6, lane = tid & 63;
  const int wm = wave >> 2, wn = wave & 3;
  const int cl = lane & 15, g = lane >> 4;

  // bijective XCD chunk swizzle (nwg % 8 == 0 for both grids)
  const int gx = gridDim.x;
  const int nwg = gx * gridDim.y;
  const int flat = blockIdx.y * gx + blockIdx.x;
  const int swzb = (flat & 7) * (nwg >> 3) + (flat >> 3);
  const int m0 = (swzb / gx) * 128;
  const int n0 = (swzb % gx) * 256;

  // stage-side geometry: thread t covers LDS elems [t*8, t*8+8) (linear dest);
  // global source chunk = (t&3) ^ ((t>>3)&3)  (inverse of the read swizzle)
  const int srow = tid >> 2;
  const int scol = (((tid & 3) ^ ((tid >> 3) & 3)) << 3);
  const short* Asrc  = A  + (size_t)(m0 + srow) * K + scol;
  const short* Bsrc0 = Bt + (size_t)(n0 + srow) * K + scol;
  const short* Bsrc1 = Bt + (size_t)(n0 + 128 + srow) * K + scol;
  const int ldso = tid * 8;

  auto stage = [&](int j) {
    const int st = j & 3;
    gl_lds16(Asrc  + j * 32, &Asm[st][ldso]);
    gl_lds16(Bsrc0 + j * 32, &Bsm[st][ldso]);
    gl_lds16(Bsrc1 + j * 32, &Bsm[st][4096 + ldso]);
  };

  // read-side swizzled chunk (row-dependence reduces to cl: (row>>1)&3 == (cl>>1)&3)
  const int rc = (g ^ ((cl >> 1) & 3)) << 3;
  const int arow = wm * 64 + cl;
  const int brow = wn * 64 + cl;

  f32x4 acc[4][4] = {};
  bf16x8 a0[4], b0[4], a1[4], b1[4];

  // prologue: subs 0,1,2 staged; publish 0,1 (vmcnt(3) leaves sub 2 in flight)
  stage(0); stage(1); stage(2);
  WAITVM(3);
  __builtin_amdgcn_s_barrier();

#define READF(AA, BB, jj) { const int _s = (jj) & 3;                          \
  _Pragma("unroll") for (int i = 0; i < 4; i++)                               \
    AA[i] = *(const bf16x8*)&Asm[_s][(arow + i * 16) * 32 + rc];              \
  _Pragma("unroll") for (int n = 0; n < 4; n++)                               \
    BB[n] = *(const bf16x8*)&Bsm[_s][(brow + n * 16) * 32 + rc]; }

#define MFMA16(AA, BB)                                                        \
  __builtin_amdgcn_s_setprio(1);                                              \
  _Pragma("unroll") for (int i = 0; i < 4; i++)                               \
    _Pragma("unroll") for (int n = 0; n < 4; n++)                             \
      acc[i][n] = __builtin_amdgcn_mfma_f32_16x16x32_bf16(AA[i], BB[n], acc[i][n], 0, 0, 0); \
  __builtin_amdgcn_s_setprio(0);

  READF(a0, b0, 0);
  for (int j = 0; j < NSUB; j += 2) {
    // phase p = j: MFMA sub j (regs a0/b0), prefetch sub j+1, stage sub j+3
    READF(a1, b1, j + 1);
    if (j + 3 < NSUB) { stage(j + 3); WAITVM(3); } else { WAITVM(0); }
    __builtin_amdgcn_s_barrier();
    MFMA16(a0, b0);

    // phase p = j+1: MFMA sub j+1, prefetch sub j+2, stage sub j+4
    if (j + 2 < NSUB) READF(a0, b0, j + 2);
    if (j + 4 < NSUB) { stage(j + 4); WAITVM(3); } else { WAITVM(0); }
    __builtin_amdgcn_s_barrier();
    MFMA16(a1, b1);
  }
#undef READF
#undef MFMA16

  // epilogue: D-layout col=lane&15, row=(lane>>4)*4+e  [m89/m91]
#pragma unroll
  for (int n = 0; n < 4; n++) {
    const int col = n0 + wn * 64 + n * 16 + cl;
    const float bs = bias[col];
#pragma unroll
    for (int i = 0; i < 4; i++) {
      const int row = m0 + wm * 64 + i * 16 + g * 4;
#pragma unroll
      for (int e = 0; e < 4; e++) {
        const float v = acc[i][n][e] + bs;
        if (BF16OUT) ((short*)Cout)[(size_t)(row + e) * N + col] = f2bf(v);
        else         ((float*)Cout)[(size_t)(row + e) * N + col] = v;
      }
    }
  }
}

// ---------------- windowed causal flash attention (unchanged, verified) -----
__global__ __launch_bounds__(256) void attn_win(
    const short* __restrict__ qkv, short* __restrict__ ctx)
{
  const int tid = threadIdx.x;
  const int wave = tid >> 6, lane = tid & 63;
  const int grp = blockIdx.x % 32;
  const int h = (blockIdx.x / 32) % NH;
  const int b = blockIdx.x / (32 * NH);
  const int qb = (grp * 4 + wave) * 16;

  const int cl = lane & 15;
  const int g  = lane >> 4;

  const size_t rowQ = (size_t)(b * S_LEN + qb + cl) * QKV_LD + h * HD;
  bf16x8 qf0 = *(const bf16x8*)&qkv[rowQ + g * 8];
  bf16x8 qf1 = *(const bf16x8*)&qkv[rowQ + 32 + g * 8];

  float m_run = -1e30f, l_run = 0.f;
  f32x4 acc[4] = {};
  const f32x4 zero = {};

  const int kstart = qb >= WIN ? qb - WIN : 0;
  const int q_glob = qb + cl;

  for (int k0 = kstart; k0 <= qb; k0 += 16) {
    const size_t rowK = (size_t)(b * S_LEN + k0 + cl) * QKV_LD + CDIM + h * HD;
    bf16x8 kf0 = *(const bf16x8*)&qkv[rowK + g * 8];
    bf16x8 kf1 = *(const bf16x8*)&qkv[rowK + 32 + g * 8];
    f32x4 st = __builtin_amdgcn_mfma_f32_16x16x32_bf16(kf0, qf0, zero, 0, 0, 0);
    st = __builtin_amdgcn_mfma_f32_16x16x32_bf16(kf1, qf1, st, 0, 0, 0);

    float s[4]; bool ok[4];
    float mt = -1e30f;
#pragma unroll
    for (int e = 0; e < 4; e++) {
      int key = k0 + 4 * g + e;
      ok[e] = (key <= q_glob) && (q_glob - key < WIN);
      s[e] = st[e] * 0.125f;
      if (ok[e]) mt = fmaxf(mt, s[e]);
    }
    mt = fmaxf(mt, __shfl_xor(mt, 16, 64));
    mt = fmaxf(mt, __shfl_xor(mt, 32, 64));
    float m_new = fmaxf(m_run, mt);
    float scale = __expf(m_run - m_new);
    float p[4]; float ls = 0.f;
#pragma unroll
    for (int e = 0; e < 4; e++) {
      p[e] = ok[e] ? __expf(s[e] - m_new) : 0.f;
      ls += p[e];
    }
    ls += __shfl_xor(ls, 16, 64);
    ls += __shfl_xor(ls, 32, 64);
    l_run = l_run * scale + ls;
    m_run = m_new;
#pragma unroll
    for (int c = 0; c < 4; c++) acc[c] *= scale;

    bf16x4 pf;
#pragma unroll
    for (int e = 0; e < 4; e++) pf[e] = f2bf(p[e]);

    const size_t rowV = (size_t)(b * S_LEN + k0 + 4 * g) * QKV_LD + 2 * CDIM + h * HD + cl;
#pragma unroll
    for (int c = 0; c < 4; c++) {
      bf16x4 vf;
#pragma unroll
      for (int e = 0; e < 4; e++)
        vf[e] = qkv[rowV + (size_t)e * QKV_LD + c * 16];
      acc[c] = __builtin_amdgcn_mfma_f32_16x16x16bf16_1k(vf, pf, acc[c], 0, 0, 0);
    }
  }

  const float inv_l = 1.f / l_run;
  const size_t rowO = (size_t)(b * S_LEN + qb + cl) * CDIM + h * HD;
#pragma unroll
  for (int c = 0; c < 4; c++)
#pragma unroll
    for (int j = 0; j < 4; j++)
      ctx[rowO + c * 16 + 4 * g + j] = f2bf(acc[c][j] * inv_l);
}

// ---------------- launcher ----------------
extern "C" void kernel_launch(void* const* d_in, const int* in_sizes, int n_in,
                              void* d_out, int out_size, void* d_ws, size_t ws_size,
                              hipStream_t stream) {
  const float* x      = (const float*)d_in[0];
  const float* W_qkv  = (const float*)d_in[1];
  const float* b_qkv  = (const float*)d_in[2];
  const float* W_proj = (const float*)d_in[3];
  const float* b_proj = (const float*)d_in[4];
  float* out = (float*)d_out;

  const int BS = 4 * S_LEN;  // 8192 rows
  char* ws = (char*)d_ws;
  short* qkv_bf = (short*)ws;                              // [8192][3072] bf16
  short* x_bf   = (short*)(ws + (size_t)BS * QKV_LD * 2);  // [8192][1024]
  short* wq_bf  = x_bf + (size_t)BS * CDIM;                // [3072][1024]
  short* wp_bf  = wq_bf + (size_t)QKV_LD * CDIM;           // [1024][1024]
  short* ctx_bf = wp_bf + (size_t)CDIM * CDIM;             // [8192][1024]

  int n4 = BS * CDIM / 4;
  cvt_f32_bf16<<<(n4 + 255) / 256, 256, 0, stream>>>(x, x_bf, n4);
  n4 = QKV_LD * CDIM / 4;
  cvt_f32_bf16<<<(n4 + 255) / 256, 256, 0, stream>>>(W_qkv, wq_bf, n4);
  n4 = CDIM * CDIM / 4;
  cvt_f32_bf16<<<(n4 + 255) / 256, 256, 0, stream>>>(W_proj, wp_bf, n4);

  dim3 g1(QKV_LD / 256, BS / 128);   // 12 x 64 = 768 blocks (3 clean rounds)
  gemm_ring<1><<<g1, 512, 0, stream>>>(x_bf, wq_bf, b_qkv, qkv_bf, QKV_LD);

  attn_win<<<4 * NH * 32, 256, 0, stream>>>(qkv_bf, ctx_bf);

  dim3 g2(CDIM / 256, BS / 128);     // 4 x 64 = 256 blocks (1 clean round)
  gemm_ring<0><<<g2, 512, 0, stream>>>(ctx_bf, wp_bf, b_proj, out, CDIM);
}